// Round 16
// baseline (562.763 us; speedup 1.0000x reference)
//
#include <hip/hip_runtime.h>
#include <hip/hip_bf16.h>
#include <cmath>
#include <cstdint>
#include <cstddef>

#define B_   4
#define L_   2048
#define E_   512
#define H_   8
#define DH_  64
#define M_   2048
#define NL_  4
#define NB_  32
#define BS_  64
#define CH_  8    // max 64-key jb-blocks per attention work item

typedef short bf16x8 __attribute__((ext_vector_type(8)));
typedef short bf16x4 __attribute__((ext_vector_type(4)));
typedef float f32x4 __attribute__((ext_vector_type(4)));

__device__ __forceinline__ short f2bf(float f) {
    union { __hip_bfloat16 h; short s; } u;
    u.h = __float2bfloat16(f);
    return u.s;
}
__device__ __forceinline__ float bf2f(short s) {
    union { short s; __hip_bfloat16 h; } u;
    u.s = s;
    return __bfloat162float(u.h);
}

// ---------------------------------------------------------------------------
// BigBird masks + work partition, all at COMPILE TIME.
// ---------------------------------------------------------------------------
struct MaskTable { unsigned m[NL_][NB_]; };
struct CxMT { unsigned key[624]; int pos; };

constexpr unsigned cx_next(CxMT& st) {
    if (st.pos >= 624) {
        for (int i = 0; i < 624; ++i) {
            unsigned y = (st.key[i] & 0x80000000u) | (st.key[(i + 1) % 624] & 0x7fffffffu);
            st.key[i] = st.key[(i + 397) % 624] ^ (y >> 1) ^ ((y & 1u) ? 0x9908b0dfu : 0u);
        }
        st.pos = 0;
    }
    unsigned y = st.key[st.pos++];
    y ^= y >> 11;
    y ^= (y << 7) & 0x9d2c5680u;
    y ^= (y << 15) & 0xefc60000u;
    y ^= y >> 18;
    return y;
}
constexpr unsigned cx_interval(CxMT& st, unsigned maxv) {
    if (maxv == 0u) return 0u;
    unsigned mask = maxv;
    mask |= mask >> 1; mask |= mask >> 2; mask |= mask >> 4;
    mask |= mask >> 8; mask |= mask >> 16;
    unsigned v = cx_next(st) & mask;
    while (v > maxv) v = cx_next(st) & mask;
    return v;
}
constexpr MaskTable compute_masks() {
    MaskTable T{};
    for (int lyr = 0; lyr < NL_; ++lyr) {
        unsigned m[NB_] = {};
        for (int i = 0; i < NB_; ++i) {
            unsigned w = 1u << i;
            if (i > 0) w |= 1u << (i - 1);
            if (i < NB_ - 1) w |= 1u << (i + 1);
            w |= 1u | (1u << (NB_ - 1));
            m[i] = w;
        }
        m[0] = 0xffffffffu;
        m[NB_ - 1] = 0xffffffffu;
        CxMT st{};
        unsigned s = (unsigned)lyr;
        for (int i = 0; i < 624; ++i) {
            st.key[i] = s;
            s = 1812433253u * (s ^ (s >> 30)) + (unsigned)i + 1u;
        }
        st.pos = 624;
        for (int i = 1; i < NB_ - 1; ++i) {
            int cand[NB_] = {};
            int n = 0;
            for (int j = 0; j < NB_; ++j) {
                if (j == 0 || j == NB_ - 1 || j == i - 1 || j == i || j == i + 1) continue;
                cand[n++] = j;
            }
            for (int kk = n - 1; kk >= 1; --kk) {
                int jj = (int)cx_interval(st, (unsigned)kk);
                int tmp = cand[kk]; cand[kk] = cand[jj]; cand[jj] = tmp;
            }
            m[i] |= (1u << cand[0]) | (1u << cand[1]) | (1u << cand[2]);
        }
        for (int i = 0; i < NB_; ++i) T.m[lyr][i] = m[i];
    }
    return T;
}

struct WorkTable {
    int n_items[NL_];
    int n_cmb[NL_];
    unsigned char itm_qb[NL_][48];
    unsigned char itm_j0[NL_][48];
    unsigned char itm_jn[NL_][48];
    unsigned char itm_slot[NL_][48];   // 0xFF = direct write to o
    unsigned char cmb_qb[NL_][8];
    unsigned char cmb_slot0[NL_][8];
    unsigned char cmb_nch[NL_][8];
    unsigned char jlist[NL_][NB_][NB_];
};

constexpr WorkTable compute_work() {
    WorkTable T{};
    MaskTable M = compute_masks();
    for (int lyr = 0; lyr < NL_; ++lyr) {
        int items = 0, slots = 0, ncmb = 0;
        for (int qb = 0; qb < NB_; ++qb) {
            int cnt = 0;
            for (int j = 0; j < NB_; ++j)
                if ((M.m[lyr][qb] >> j) & 1u)
                    T.jlist[lyr][qb][cnt++] = (unsigned char)j;
            int nch = (cnt + CH_ - 1) / CH_;
            if (nch == 1) {
                T.itm_qb[lyr][items] = (unsigned char)qb;
                T.itm_j0[lyr][items] = 0;
                T.itm_jn[lyr][items] = (unsigned char)cnt;
                T.itm_slot[lyr][items] = 0xFF;
                items++;
            } else {
                T.cmb_qb[lyr][ncmb] = (unsigned char)qb;
                T.cmb_slot0[lyr][ncmb] = (unsigned char)slots;
                T.cmb_nch[lyr][ncmb] = (unsigned char)nch;
                ncmb++;
                int base = cnt / nch, rem = cnt % nch, off = 0;
                for (int c = 0; c < nch; ++c) {
                    int cl = base + (c < rem ? 1 : 0);
                    T.itm_qb[lyr][items] = (unsigned char)qb;
                    T.itm_j0[lyr][items] = (unsigned char)off;
                    T.itm_jn[lyr][items] = (unsigned char)cl;
                    T.itm_slot[lyr][items] = (unsigned char)slots;
                    items++; slots++; off += cl;
                }
            }
        }
        T.n_items[lyr] = items;
        T.n_cmb[lyr] = ncmb;
    }
    return T;
}

static constexpr WorkTable WT_HOST = compute_work();
__constant__ WorkTable g_wt = compute_work();

// ---------------------------------------------------------------------------
// Embedding + sinusoidal PE -> bf16 residual stream x
// ---------------------------------------------------------------------------
__global__ __launch_bounds__(256) void embed_kernel(const int* __restrict__ tokens,
                                                    const float* __restrict__ embed,
                                                    short* __restrict__ x) {
    int idx = blockIdx.x * 256 + threadIdx.x;      // < L_*E_/8 = 131072
    int l = idx >> 6;
    int e0 = (idx & 63) * 8;
    float pe[8];
    #pragma unroll
    for (int j = 0; j < 8; ++j) {
        int e = e0 + j;
        int jj = e & 255;
        float div = expf((float)jj * -0.03597789207717895f);  // -ln(10000)/256
        float arg = (float)l * div;
        pe[j] = (e < 256) ? sinf(arg) : cosf(arg);
    }
    #pragma unroll
    for (int b = 0; b < B_; ++b) {
        int tok = tokens[b * L_ + l];
        const float* em = embed + (size_t)tok * E_ + e0;
        f32x4 v0 = *(const f32x4*)em;
        f32x4 v1 = *(const f32x4*)(em + 4);
        bf16x8 pk;
        #pragma unroll
        for (int j = 0; j < 4; ++j) {
            pk[j] = f2bf(v0[j] + pe[j]);
            pk[4 + j] = f2bf(v1[j] + pe[4 + j]);
        }
        *(bf16x8*)(x + ((size_t)(b * L_ + l)) * E_ + e0) = pk;
    }
}

// ---------------------------------------------------------------------------
// LayerNorm: bf16 input, bf16 (OUTBF=1) or fp32 (OUTBF=0) output.
// Wave-per-row (4 rows per 256-thread block, no barriers).
// ---------------------------------------------------------------------------
template<int OUTBF>
__global__ __launch_bounds__(256) void ln_kernel(const short* __restrict__ x,
                                                 const float* __restrict__ gamma,
                                                 const float* __restrict__ beta,
                                                 void* __restrict__ yout) {
    int t = threadIdx.x;
    int lane = t & 63;
    int row = blockIdx.x * 4 + (t >> 6);
    bf16x8 av = *(const bf16x8*)(x + (size_t)row * E_ + lane * 8);
    float a[8];
    #pragma unroll
    for (int j = 0; j < 8; ++j) a[j] = bf2f(av[j]);
    float s = ((a[0] + a[1]) + (a[2] + a[3])) + ((a[4] + a[5]) + (a[6] + a[7]));
    #pragma unroll
    for (int off = 1; off < 64; off <<= 1) s += __shfl_xor(s, off, 64);
    float mu = s * (1.0f / E_);
    float q = 0.0f;
    #pragma unroll
    for (int j = 0; j < 8; ++j) { float d = a[j] - mu; q += d * d; }
    #pragma unroll
    for (int off = 1; off < 64; off <<= 1) q += __shfl_xor(q, off, 64);
    float rstd = rsqrtf(q * (1.0f / E_) + 1e-6f);
    f32x4 g0 = *(const f32x4*)(gamma + lane * 8);
    f32x4 g1 = *(const f32x4*)(gamma + lane * 8 + 4);
    f32x4 b0 = *(const f32x4*)(beta + lane * 8);
    f32x4 b1 = *(const f32x4*)(beta + lane * 8 + 4);
    float o[8];
    #pragma unroll
    for (int j = 0; j < 4; ++j) o[j] = (a[j] - mu) * rstd * g0[j] + b0[j];
    #pragma unroll
    for (int j = 0; j < 4; ++j) o[4 + j] = (a[4 + j] - mu) * rstd * g1[j] + b1[j];
    if (OUTBF) {
        bf16x8 pk;
        #pragma unroll
        for (int j = 0; j < 8; ++j) pk[j] = f2bf(o[j]);
        *(bf16x8*)((short*)yout + (size_t)row * E_ + lane * 8) = pk;
    } else {
        float* yr = (float*)yout + (size_t)row * E_ + lane * 8;
        *(f32x4*)yr = f32x4{o[0], o[1], o[2], o[3]};
        *(f32x4*)(yr + 4) = f32x4{o[4], o[5], o[6], o[7]};
    }
}

// ---------------------------------------------------------------------------
// Weight convert + transpose: Wt[n][k] = bf16(W[k][n] * scale), per layer (z)
// ---------------------------------------------------------------------------
__global__ __launch_bounds__(256) void convT_kernel(const float* __restrict__ W,
                                                    short* __restrict__ Wt,
                                                    int K, int N,
                                                    size_t wStride, size_t wtStride,
                                                    float scale) {
    __shared__ float Ts[64][65];
    const float* Wl = W + blockIdx.z * wStride;
    short* Wtl = Wt + blockIdx.z * wtStride;
    int n0 = blockIdx.x * 64, k0 = blockIdx.y * 64;
    int t = threadIdx.x;
    int c = t & 63, r0 = t >> 6;
    #pragma unroll
    for (int i = 0; i < 16; ++i) {
        int r = r0 * 16 + i;
        Ts[r][c] = Wl[(size_t)(k0 + r) * N + n0 + c] * scale;
    }
    __syncthreads();
    #pragma unroll
    for (int i = 0; i < 16; ++i) {
        int r = r0 * 16 + i;
        Wtl[(size_t)(n0 + r) * K + k0 + c] = f2bf(Ts[c][r]);
    }
}

// ---------------------------------------------------------------------------
// MFMA bf16 GEMM, 2-phase double-buffered (r12-proven schedule, UNCHANGED).
// ---------------------------------------------------------------------------
__device__ __forceinline__ float gelu_tanh(float x) {
    float u = x * (1.5957691216057308f + 0.07135480122394604f * x * x);
    return x / (1.0f + __expf(-u));
}

template<int BM, int BN, int ACT, int OUTBF>
__global__ __launch_bounds__(512) void mgemm_kernel(const short* __restrict__ A,
                                                    const short* __restrict__ Bt,
                                                    const float* __restrict__ bias,
                                                    const short* __restrict__ res,
                                                    short* __restrict__ Cout,
                                                    int M, int N, int K) {
    constexpr int WR = 2, WC = 4;      // 8 waves
    constexpr int FM = BM / WR / 16;
    constexpr int FN = BN / WC / 16;
    constexpr int ASZ = BM * 64;
    constexpr int BSZ = BN * 64;
    constexpr int PAD = 8;
    constexpr int CW = BN + PAD;
    static_assert((size_t)(OUTBF ? BM * CW * 2 : BM * CW * 4) <= (size_t)2 * (ASZ + BSZ) * 2,
                  "epilogue stage must fit in dbuf LDS");
    __shared__ __align__(16) short smem[2 * (ASZ + BSZ)];

    int t = threadIdx.x;
    int w = t >> 6, l = t & 63;
    int l15 = l & 15, lg = l >> 4;
    int wr = w >> 2, wc = w & 3;
    int rowbase = wr * (BM / WR), colbase = wc * (BN / WC);

    int nwg = (int)(gridDim.x * gridDim.y);
    int orig = (int)(blockIdx.y * gridDim.x + blockIdx.x);
    int sid = (orig & 7) * (nwg >> 3) + (orig >> 3);
    int bx = sid % (int)gridDim.x, by = sid / (int)gridDim.x;
    int brow = by * BM, bcol = bx * BN;

    int swz = ((t & 7) ^ ((t >> 3) & 7)) * 8;
    f32x4 acc[FM][FN] = {};

    const int nt = K >> 6;

    auto stage = [&](int buf, int k0) {
        short* Ad = smem + buf * ASZ;
        short* Bd = smem + 2 * ASZ + buf * BSZ;
        #pragma unroll
        for (int it = 0; it < BM / 64; ++it) {
            int row = it * 64 + (t >> 3);
            const short* ga = A + (size_t)(brow + row) * K + k0 + swz;
            __builtin_amdgcn_global_load_lds(
                (const __attribute__((address_space(1))) unsigned int*)ga,
                (__attribute__((address_space(3))) unsigned int*)(Ad + (it * 64 + w * 8) * 64),
                16, 0, 0);
        }
        #pragma unroll
        for (int it = 0; it < BN / 64; ++it) {
            int row = it * 64 + (t >> 3);
            const short* gb = Bt + (size_t)(bcol + row) * K + k0 + swz;
            __builtin_amdgcn_global_load_lds(
                (const __attribute__((address_space(1))) unsigned int*)gb,
                (__attribute__((address_space(3))) unsigned int*)(Bd + (it * 64 + w * 8) * 64),
                16, 0, 0);
        }
    };

    stage(0, 0);
    asm volatile("s_waitcnt vmcnt(0)" ::: "memory");
    __builtin_amdgcn_s_barrier();

    int cur = 0;
    for (int kt = 0; kt < nt; ++kt) {
        if (kt + 1 < nt) stage(cur ^ 1, (kt + 1) << 6);
        const short* Ar = smem + cur * ASZ;
        const short* Br = smem + 2 * ASZ + cur * BSZ;
        #pragma unroll
        for (int kk = 0; kk < 64; kk += 32) {
            bf16x8 af[FM], bfr[FN];
            #pragma unroll
            for (int m = 0; m < FM; ++m)
                af[m] = *(const bf16x8*)(Ar + (rowbase + m * 16 + l15) * 64
                                            + (((kk >> 3) + lg) ^ (l15 & 7)) * 8);
            #pragma unroll
            for (int n = 0; n < FN; ++n)
                bfr[n] = *(const bf16x8*)(Br + (colbase + n * 16 + l15) * 64
                                             + (((kk >> 3) + lg) ^ (l15 & 7)) * 8);
            #pragma unroll
            for (int m = 0; m < FM; ++m)
                #pragma unroll
                for (int n = 0; n < FN; ++n)
                    acc[m][n] = __builtin_amdgcn_mfma_f32_16x16x32_bf16(af[m], bfr[n], acc[m][n], 0, 0, 0);
        }
        asm volatile("s_waitcnt vmcnt(0) lgkmcnt(0)" ::: "memory");
        __builtin_amdgcn_s_barrier();
        cur ^= 1;
    }

    if (OUTBF) {
        short* Cs = smem;
        #pragma unroll
        for (int m = 0; m < FM; ++m) {
            int row = rowbase + m * 16 + lg * 4;
            #pragma unroll
            for (int n = 0; n < FN; ++n) {
                int col = colbase + n * 16 + l15;
                float bv = bias ? bias[bcol + col] : 0.0f;
                #pragma unroll
                for (int r = 0; r < 4; ++r) {
                    float vv = acc[m][n][r] + bv;
                    if (ACT == 1) vv = gelu_tanh(vv);
                    Cs[(row + r) * CW + col] = f2bf(vv);
                }
            }
        }
        __syncthreads();
        #pragma unroll
        for (int it = 0; it < BM * BN / 8 / 512; ++it) {
            int c = it * 512 + t;
            int row = c / (BN / 8), c8 = c % (BN / 8);
            *(bf16x8*)(Cout + (size_t)(brow + row) * N + bcol + c8 * 8) =
                *(const bf16x8*)(Cs + row * CW + c8 * 8);
        }
    } else {
        float* Cs = (float*)smem;              // f32 staging: single rounding
        #pragma unroll
        for (int m = 0; m < FM; ++m) {
            int row = rowbase + m * 16 + lg * 4;
            #pragma unroll
            for (int n = 0; n < FN; ++n) {
                int col = colbase + n * 16 + l15;
                float bv = bias ? bias[bcol + col] : 0.0f;
                #pragma unroll
                for (int r = 0; r < 4; ++r)
                    Cs[(row + r) * CW + col] = acc[m][n][r] + bv;
            }
        }
        __syncthreads();
        #pragma unroll
        for (int it = 0; it < BM * BN / 8 / 512; ++it) {
            int c = it * 512 + t;
            int row = c / (BN / 8), c8 = c % (BN / 8);
            const float* cr = Cs + row * CW + c8 * 8;
            size_t gi = (size_t)(brow + row) * N + bcol + c8 * 8;
            bf16x8 rv = {};
            if (res) rv = *(const bf16x8*)(res + gi);
            bf16x8 outv;
            #pragma unroll
            for (int j = 0; j < 8; ++j) {
                float v = cr[j] + (res ? bf2f(rv[j]) : 0.0f);
                outv[j] = f2bf(v);
            }
            *(bf16x8*)(Cout + gi) = outv;
        }
    }
}

// ---------------------------------------------------------------------------
// Sparse block attention, MFMA bf16, KVBLK=64, swapped QK^T, dbuf K/V LDS.
// Flat 1-D grid + bijective XCD chunk swizzle; tree reductions + defer-max.
// NEW (r16): P re-layout D->A via in-register cross-lane shuffles (8x u64
// __shfl over lanes {l15+16*lg'}) -- Pw LDS tile REMOVED (46.6->37.1 KB,
// 3->4 blocks/CU) and the ds_write->ds_read RAW wait leaves the chain.
// ---------------------------------------------------------------------------
#define KSTR 72

__global__ __launch_bounds__(256) void attn_kernel(const short* __restrict__ qkv,
                                                   const int* __restrict__ tokens,
                                                   short* __restrict__ o,
                                                   float* __restrict__ pacc,
                                                   float* __restrict__ pm,
                                                   float* __restrict__ pl,
                                                   int lyr) {
    __shared__ __align__(16) short Ks[2][64][KSTR];
    __shared__ __align__(16) short Vt[2][64][KSTR];
    __shared__ unsigned long long qbits_s;
    __shared__ unsigned long long kbits_s[2];

    int nit = g_wt.n_items[lyr];
    int nwg = (int)gridDim.x;                    // nit * 32, divisible by 8
    int orig = (int)blockIdx.x;
    int sid = (orig & 7) * (nwg >> 3) + (orig >> 3);
    int item = sid % nit;
    int bh = sid / nit;
    int h = bh & 7, b = bh >> 3;

    int qb   = g_wt.itm_qb[lyr][item];
    int j0   = g_wt.itm_j0[lyr][item];
    int jn   = g_wt.itm_jn[lyr][item];
    int slot = g_wt.itm_slot[lyr][item];
    const unsigned char* jl = g_wt.jlist[lyr][qb];

    int t = threadIdx.x;
    int l = t & 63, w = t >> 6;
    int l15 = l & 15, lg = l >> 4;
    int srow = t >> 3, sdb = t & 7;

    if (t < 64) {
        unsigned long long qm = __ballot(tokens[b * L_ + qb * 64 + t] > 0);
        if (t == 0) qbits_s = qm;
    }

    int qrow = qb * 64 + w * 16 + l15;
    const short* qp = qkv + (size_t)(b * L_ + qrow) * 1536 + h * 64;
    bf16x8 qf0 = *(const bf16x8*)(qp + lg * 8);
    bf16x8 qf1 = *(const bf16x8*)(qp + lg * 8 + 32);

    f32x4 acc[4] = {};
    float m_r = -INFINITY, l_r = 0.0f;

    bf16x8 kr0, kr1, vr0, vr1;
    int pn = 0;
    auto LOAD = [&](int ci) {
        int jb = jl[j0 + ci];
        const short* base = qkv + (size_t)(b * L_ + jb * 64 + srow) * 1536 + h * 64;
        kr0 = *(const bf16x8*)(base + 512 + sdb * 8);
        kr1 = *(const bf16x8*)(base + (size_t)32 * 1536 + 512 + sdb * 8);
        vr0 = *(const bf16x8*)(base + 1024 + sdb * 8);
        vr1 = *(const bf16x8*)(base + (size_t)32 * 1536 + 1024 + sdb * 8);
        if (t < 64) pn = tokens[b * L_ + jb * 64 + t];
    };
    auto STORE = [&](int buf) {
        *(bf16x8*)&Ks[buf][srow][sdb * 8] = kr0;
        *(bf16x8*)&Ks[buf][srow + 32][sdb * 8] = kr1;
        #pragma unroll
        for (int j = 0; j < 8; ++j) {
            Vt[buf][sdb * 8 + j][(srow & 7) + 8 * ((srow >> 3) ^ sdb)] = vr0[j];
            Vt[buf][sdb * 8 + j][(srow & 7) + 8 * (((srow >> 3) + 4) ^ sdb)] = vr1[j];
        }
        if (t < 64) {
            unsigned long long km = __ballot(pn > 0);
            if (t == 0) kbits_s[buf] = km;
        }
    };

    LOAD(0);
    STORE(0);
    if (jn > 1) LOAD(1);
    __syncthreads();

    int cur = 0;
    for (int ci = 0; ci < jn; ++ci) {
        f32x4 sacc[4];
        __builtin_amdgcn_s_setprio(1);
        #pragma unroll
        for (int f = 0; f < 4; ++f) {
            bf16x8 kk0 = *(const bf16x8*)&Ks[cur][16 * f + l15][lg * 8];
            bf16x8 kk1 = *(const bf16x8*)&Ks[cur][16 * f + l15][lg * 8 + 32];
            f32x4 z = {};
            z = __builtin_amdgcn_mfma_f32_16x16x32_bf16(kk0, qf0, z, 0, 0, 0);
            z = __builtin_amdgcn_mfma_f32_16x16x32_bf16(kk1, qf1, z, 0, 0, 0);
            sacc[f] = z;
        }
        __builtin_amdgcn_s_setprio(0);

        unsigned long long kb = kbits_s[cur];
        bool pq = (qbits_s >> (w * 16 + l15)) & 1ull;
        unsigned vm = 0;
        #pragma unroll
        for (int f = 0; f < 4; ++f)
            vm |= ((unsigned)(kb >> (16 * f + 4 * lg)) & 0xFu) << (4 * f);
        if (!pq) vm = 0;

        float sv[16];
        #pragma unroll
        for (int i = 0; i < 16; ++i)
            sv[i] = ((vm >> i) & 1u) ? sacc[i >> 2][i & 3] : -INFINITY;
        float t8[8], t4[4];
        #pragma unroll
        for (int i = 0; i < 8; ++i) t8[i] = fmaxf(sv[i], sv[i + 8]);
        #pragma unroll
        for (int i = 0; i < 4; ++i) t4[i] = fmaxf(t8[i], t8[i + 4]);
        float mx = fmaxf(fmaxf(t4[0], t4[1]), fmaxf(t4[2], t4[3]));
        mx = fmaxf(mx, __shfl_xor(mx, 16, 64));
        mx = fmaxf(mx, __shfl_xor(mx, 32, 64));

        bool defer = __all((mx <= m_r + 8.0f) && (m_r > -1e30f));
        float nm = defer ? m_r : fmaxf(m_r, mx);

        float pv[16];
        #pragma unroll
        for (int i = 0; i < 16; ++i)
            pv[i] = ((vm >> i) & 1u) ? __expf(sv[i] - nm) : 0.0f;
        float s8[8], s4[4];
        #pragma unroll
        for (int i = 0; i < 8; ++i) s8[i] = pv[i] + pv[i + 8];
        #pragma unroll
        for (int i = 0; i < 4; ++i) s4[i] = s8[i] + s8[i + 4];
        float sum = (s4[0] + s4[1]) + (s4[2] + s4[3]);
        sum += __shfl_xor(sum, 16, 64);
        sum += __shfl_xor(sum, 32, 64);

        if (defer) {
            l_r += sum;
        } else {
            float al = (nm == -INFINITY) ? 1.0f : __expf(m_r - nm);
            m_r = nm;
            l_r = l_r * al + sum;
            float alr[4];
            #pragma unroll
            for (int r = 0; r < 4; ++r) alr[r] = __shfl(al, lg * 4 + r, 64);
            #pragma unroll
            for (int fd = 0; fd < 4; ++fd)
                #pragma unroll
                for (int r = 0; r < 4; ++r) acc[fd][r] *= alr[r];
        }

        // ---- P re-layout D->A in registers (replaces Pw LDS round-trip) ----
        // pk64[f] packs keys {16f+4lg+0..3} (bf16x4) for qrow l15.
        // pa0 needs keys 8lg..8lg+7 -> f'=lg>>1, sources lg'=(lg&1)*2, +1.
        // pa1 needs keys 32+8lg..+7 -> f''=2+(lg>>1), same sources.
        unsigned long long pk64[4];
        #pragma unroll
        for (int f = 0; f < 4; ++f) {
            unsigned lo = (unsigned)(unsigned short)f2bf(pv[4 * f + 0]) |
                          ((unsigned)(unsigned short)f2bf(pv[4 * f + 1]) << 16);
            unsigned hi = (unsigned)(unsigned short)f2bf(pv[4 * f + 2]) |
                          ((unsigned)(unsigned short)f2bf(pv[4 * f + 3]) << 16);
            pk64[f] = (unsigned long long)lo | ((unsigned long long)hi << 32);
        }
        int src_lo = l15 + 16 * ((lg & 1) << 1);
        int src_hi = src_lo + 16;
        unsigned long long e_lo[4], e_hi[4];
        #pragma unroll
        for (int f = 0; f < 4; ++f) {
            e_lo[f] = __shfl((long long)pk64[f], src_lo, 64);
            e_hi[f] = __shfl((long long)pk64[f], src_hi, 64);
        }
        bool fs = (lg >> 1) & 1;
        unsigned long long a0lo = fs ? e_lo[1] : e_lo[0];
        unsigned long long a0hi = fs ? e_hi[1] : e_hi[0];
        unsigned long long a1lo = fs ? e_lo[3] : e_lo[2];
        unsigned long long a1hi = fs ? e_hi[3] : e_hi[2];
        union { unsigned long long q[2]; bf16x8 v; } ua0, ua1;
        ua0.q[0] = a0lo; ua0.q[1] = a0hi;
        ua1.q[0] = a1lo; ua1.q[1] = a1hi;
        bf16x8 pa0 = ua0.v, pa1 = ua1.v;

        __builtin_amdgcn_s_setprio(1);
        #pragma unroll
        for (int fd = 0; fd < 4; ++fd) {
            int dd = 16 * fd + l15;
            bf16x8 vv0 = *(const bf16x8*)&Vt[cur][dd][8 * (lg ^ (dd >> 3))];
            bf16x8 vv1 = *(const bf16x8*)&Vt[cur][dd][8 * ((4 + lg) ^ (dd >> 3))];
            acc[fd] = __builtin_amdgcn_mfma_f32_16x16x32_bf16(pa0, vv0, acc[fd], 0, 0, 0);
            acc[fd] = __builtin_amdgcn_mfma_f32_16x16x32_bf16(pa1, vv1, acc[fd], 0, 0, 0);
        }
        __builtin_amdgcn_s_setprio(0);

        if (ci + 1 < jn) {
            STORE(cur ^ 1);
            if (ci + 2 < jn) LOAD(ci + 2);
        }
        __syncthreads();
        cur ^= 1;
    }

    float lrr[4], mrr[4];
    #pragma unroll
    for (int r = 0; r < 4; ++r) {
        lrr[r] = __shfl(l_r, lg * 4 + r, 64);
        mrr[r] = __shfl(m_r, lg * 4 + r, 64);
    }
    unsigned long long qbits = qbits_s;

    if (slot == 0xFF) {
        #pragma unroll
        for (int r = 0; r < 4; ++r) {
            int rw = lg * 4 + r;
            int gl = qb * 64 + w * 16 + rw;
            size_t ob = (size_t)(b * L_ + gl) * 512 + h * 64 + l15;
            bool ok = ((qbits >> (w * 16 + rw)) & 1ull) && (lrr[r] > 0.0f);
            if (ok) {
                float inv = 1.0f / lrr[r];
                #pragma unroll
                for (int fd = 0; fd < 4; ++fd) o[ob + 16 * fd] = f2bf(acc[fd][r] * inv);
            } else {
                #pragma unroll
                for (int fd = 0; fd < 4; ++fd) {
                    float s = 0.0f;
                    for (int m = 0; m < L_; ++m)
                        s += bf2f(qkv[(size_t)(b * L_ + m) * 1536 + 1024 + h * 64 + 16 * fd + l15]);
                    o[ob + 16 * fd] = f2bf(s * (1.0f / L_));
                }
            }
        }
    } else {
        size_t pb = ((size_t)slot * B_ + b) * H_ + h;
        #pragma unroll
        for (int r = 0; r < 4; ++r) {
            int rloc = w * 16 + lg * 4 + r;
            #pragma unroll
            for (int fd = 0; fd < 4; ++fd)
                pacc[pb * 4096 + (size_t)rloc * 64 + 16 * fd + l15] = acc[fd][r];
            if (l15 == 0) {
                pm[pb * 64 + rloc] = mrr[r];
                pl[pb * 64 + rloc] = lrr[r];
            }
        }
    }
}

// ---------------------------------------------------------------------------
// Combine partial flash results for split q-blocks.
// ---------------------------------------------------------------------------
__global__ __launch_bounds__(256) void attn_combine(const short* __restrict__ qkv,
                                                    const int* __restrict__ tokens,
                                                    short* __restrict__ o,
                                                    const float* __restrict__ pacc,
                                                    const float* __restrict__ pm,
                                                    const float* __restrict__ pl,
                                                    int lyr) {
    int ci = blockIdx.x, h = blockIdx.y, b = blockIdx.z;
    int qb  = g_wt.cmb_qb[lyr][ci];
    int s0  = g_wt.cmb_slot0[lyr][ci];
    int nch = g_wt.cmb_nch[lyr][ci];
    int t = threadIdx.x;
    int r = t >> 2, dq = t & 3;
    int grow = qb * 64 + r;
    bool pq = tokens[b * L_ + grow] > 0;
    float M = -INFINITY;
    for (int c = 0; c < nch; ++c)
        M = fmaxf(M, pm[(((size_t)(s0 + c) * B_ + b) * H_ + h) * 64 + r]);
    size_t ob = (size_t)(b * L_ + grow) * 512 + h * 64 + dq * 16;
    if (pq && M > -1e30f) {
        float lsum = 0.0f;
        float accd[16] = {};
        for (int c = 0; c < nch; ++c) {
            size_t pb = ((size_t)(s0 + c) * B_ + b) * H_ + h;
            float wgt = __expf(pm[pb * 64 + r] - M);
            lsum += pl[pb * 64 + r] * wgt;
            const float* pa = pacc + pb * 4096 + (size_t)r * 64 + dq * 16;
            #pragma unroll
            for (int j = 0; j < 16; ++j) accd[j] += pa[j] * wgt;
        }
        float inv = 1.0f / lsum;
        #pragma unroll
        for (int j = 0; j < 16; ++j) o[ob + j] = f2bf(accd[j] * inv);
    } else {
        #pragma unroll
        for (int j = 0; j < 16; ++j) {
            float s = 0.0f;
            for (int m = 0; m < L_; ++m)
                s += bf2f(qkv[(size_t)(b * L_ + m) * 1536 + 1024 + h * 64 + dq * 16 + j]);
            o[ob + j] = f2bf(s * (1.0f / L_));
        }
    }
}

// ---------------------------------------------------------------------------
// Launch
// ---------------------------------------------------------------------------
extern "C" void kernel_launch(void* const* d_in, const int* in_sizes, int n_in,
                              void* d_out, int out_size, void* d_ws, size_t ws_size,
                              hipStream_t stream) {
    (void)in_sizes; (void)n_in; (void)out_size; (void)ws_size;
    const int*   tokens = (const int*)d_in[0];
    const float* embed  = (const float*)d_in[1];
    const float* ln1_s  = (const float*)d_in[2];
    const float* ln1_b  = (const float*)d_in[3];
    const float* wq     = (const float*)d_in[4];
    const float* wk     = (const float*)d_in[5];
    const float* wv     = (const float*)d_in[6];
    const float* wo     = (const float*)d_in[7];
    const float* ln2_s  = (const float*)d_in[8];
    const float* ln2_b  = (const float*)d_in[9];
    const float* w1     = (const float*)d_in[10];
    const float* b1     = (const float*)d_in[11];
    const float* w2     = (const float*)d_in[12];
    const float* b2     = (const float*)d_in[13];
    const float* lnf_s  = (const float*)d_in[14];
    const float* lnf_b  = (const float*)d_in[15];
    float* out = (float*)d_out;

    const size_t BLE = (size_t)B_ * L_ * E_;              // 4,194,304
    char* ws = (char*)d_ws;
    short* x    = (short*)ws;                             // bf16 residual, 8 MB
    short* yb   = x + BLE;                                //  8 MB
    short* R    = yb + BLE;                               // 32 MB (qkv+ob / hb)
    short* qkv  = R;
    short* ob   = R + 3 * BLE;
    short* hb   = R;
    short* qkvt = R + 4 * BLE;                            // bf16 weights
    short* wot  = qkvt + (size_t)NL_ * 1536 * 512;
    short* w1t  = wot + (size_t)NL_ * 512 * 512;
    short* w2t  = w1t + (size_t)NL_ * 2048 * 512;
    float* pacc = (float*)(w2t + (size_t)NL_ * 512 * 2048);   // 8 slots x B x H x 4096 f32
    float* pm   = pacc + (size_t)8 * B_ * H_ * 4096;
    float* pl   = pm + (size_t)8 * B_ * H_ * 64;

    convT_kernel<<<dim3(8, 8, NL_), 256, 0, stream>>>(wq, qkvt,          512, 512, 262144, 786432, 0.125f);
    convT_kernel<<<dim3(8, 8, NL_), 256, 0, stream>>>(wk, qkvt + 262144, 512, 512, 262144, 786432, 1.0f);
    convT_kernel<<<dim3(8, 8, NL_), 256, 0, stream>>>(wv, qkvt + 524288, 512, 512, 262144, 786432, 1.0f);
    convT_kernel<<<dim3(8, 8, NL_), 256, 0, stream>>>(wo, wot,           512, 512, 262144, 262144, 1.0f);
    convT_kernel<<<dim3(32, 8, NL_), 256, 0, stream>>>(w1, w1t,          512, 2048, 1048576, 1048576, 1.0f);
    convT_kernel<<<dim3(8, 32, NL_), 256, 0, stream>>>(w2, w2t,          2048, 512, 1048576, 1048576, 1.0f);

    embed_kernel<<<(L_ * E_ / 8) / 256, 256, 0, stream>>>(tokens, embed, x);

    const int MR = B_ * L_;
    const int LNG = MR / 4;                                // 2048 blocks
    for (int lyr = 0; lyr < NL_; ++lyr) {
        ln_kernel<1><<<LNG, 256, 0, stream>>>(x, ln1_s + lyr * E_, ln1_b + lyr * E_, yb);
        mgemm_kernel<128, 128, 0, 1><<<dim3(12, 64), 512, 0, stream>>>(
            yb, qkvt + (size_t)lyr * 786432, nullptr, nullptr, qkv, MR, 1536, 512);
        attn_kernel<<<dim3(WT_HOST.n_items[lyr] * H_ * B_), 256, 0, stream>>>(
            qkv, tokens, ob, pacc, pm, pl, lyr);
        attn_combine<<<dim3(WT_HOST.n_cmb[lyr], H_, B_), 256, 0, stream>>>(
            qkv, tokens, ob, pacc, pm, pl, lyr);
        mgemm_kernel<64, 128, 0, 0><<<dim3(4, 128), 512, 0, stream>>>(
            ob, wot + (size_t)lyr * 262144, nullptr, x, x, MR, 512, 512);
        ln_kernel<1><<<LNG, 256, 0, stream>>>(x, ln2_s + lyr * E_, ln2_b + lyr * E_, yb);
        mgemm_kernel<128, 128, 1, 1><<<dim3(16, 64), 512, 0, stream>>>(
            yb, w1t + (size_t)lyr * 1048576, b1 + (size_t)lyr * M_, nullptr, hb, MR, 2048, 512);
        mgemm_kernel<64, 128, 0, 0><<<dim3(4, 128), 512, 0, stream>>>(
            hb, w2t + (size_t)lyr * 1048576, b2 + (size_t)lyr * E_, x, x, MR, 512, 2048);
    }
    ln_kernel<0><<<LNG, 256, 0, stream>>>(x, lnf_s, lnf_b, out);
}

// Round 17
// 554.766 us; speedup vs baseline: 1.0144x; 1.0144x over previous
//
#include <hip/hip_runtime.h>
#include <hip/hip_bf16.h>
#include <cmath>
#include <cstdint>
#include <cstddef>

#define B_   4
#define L_   2048
#define E_   512
#define H_   8
#define DH_  64
#define M_   2048
#define NL_  4
#define NB_  32
#define BS_  64
#define CH_  8    // max 64-key jb-blocks per attention work item

typedef short bf16x8 __attribute__((ext_vector_type(8)));
typedef short bf16x4 __attribute__((ext_vector_type(4)));
typedef float f32x4 __attribute__((ext_vector_type(4)));

__device__ __forceinline__ short f2bf(float f) {
    union { __hip_bfloat16 h; short s; } u;
    u.h = __float2bfloat16(f);
    return u.s;
}
__device__ __forceinline__ float bf2f(short s) {
    union { short s; __hip_bfloat16 h; } u;
    u.s = s;
    return __bfloat162float(u.h);
}

// ---------------------------------------------------------------------------
// BigBird masks + work partition, all at COMPILE TIME.
// ---------------------------------------------------------------------------
struct MaskTable { unsigned m[NL_][NB_]; };
struct CxMT { unsigned key[624]; int pos; };

constexpr unsigned cx_next(CxMT& st) {
    if (st.pos >= 624) {
        for (int i = 0; i < 624; ++i) {
            unsigned y = (st.key[i] & 0x80000000u) | (st.key[(i + 1) % 624] & 0x7fffffffu);
            st.key[i] = st.key[(i + 397) % 624] ^ (y >> 1) ^ ((y & 1u) ? 0x9908b0dfu : 0u);
        }
        st.pos = 0;
    }
    unsigned y = st.key[st.pos++];
    y ^= y >> 11;
    y ^= (y << 7) & 0x9d2c5680u;
    y ^= (y << 15) & 0xefc60000u;
    y ^= y >> 18;
    return y;
}
constexpr unsigned cx_interval(CxMT& st, unsigned maxv) {
    if (maxv == 0u) return 0u;
    unsigned mask = maxv;
    mask |= mask >> 1; mask |= mask >> 2; mask |= mask >> 4;
    mask |= mask >> 8; mask |= mask >> 16;
    unsigned v = cx_next(st) & mask;
    while (v > maxv) v = cx_next(st) & mask;
    return v;
}
constexpr MaskTable compute_masks() {
    MaskTable T{};
    for (int lyr = 0; lyr < NL_; ++lyr) {
        unsigned m[NB_] = {};
        for (int i = 0; i < NB_; ++i) {
            unsigned w = 1u << i;
            if (i > 0) w |= 1u << (i - 1);
            if (i < NB_ - 1) w |= 1u << (i + 1);
            w |= 1u | (1u << (NB_ - 1));
            m[i] = w;
        }
        m[0] = 0xffffffffu;
        m[NB_ - 1] = 0xffffffffu;
        CxMT st{};
        unsigned s = (unsigned)lyr;
        for (int i = 0; i < 624; ++i) {
            st.key[i] = s;
            s = 1812433253u * (s ^ (s >> 30)) + (unsigned)i + 1u;
        }
        st.pos = 624;
        for (int i = 1; i < NB_ - 1; ++i) {
            int cand[NB_] = {};
            int n = 0;
            for (int j = 0; j < NB_; ++j) {
                if (j == 0 || j == NB_ - 1 || j == i - 1 || j == i || j == i + 1) continue;
                cand[n++] = j;
            }
            for (int kk = n - 1; kk >= 1; --kk) {
                int jj = (int)cx_interval(st, (unsigned)kk);
                int tmp = cand[kk]; cand[kk] = cand[jj]; cand[jj] = tmp;
            }
            m[i] |= (1u << cand[0]) | (1u << cand[1]) | (1u << cand[2]);
        }
        for (int i = 0; i < NB_; ++i) T.m[lyr][i] = m[i];
    }
    return T;
}

struct WorkTable {
    int n_items[NL_];
    int n_cmb[NL_];
    unsigned char itm_qb[NL_][48];
    unsigned char itm_j0[NL_][48];
    unsigned char itm_jn[NL_][48];
    unsigned char itm_slot[NL_][48];   // 0xFF = direct write to o
    unsigned char cmb_qb[NL_][8];
    unsigned char cmb_slot0[NL_][8];
    unsigned char cmb_nch[NL_][8];
    unsigned char jlist[NL_][NB_][NB_];
};

constexpr WorkTable compute_work() {
    WorkTable T{};
    MaskTable M = compute_masks();
    for (int lyr = 0; lyr < NL_; ++lyr) {
        int items = 0, slots = 0, ncmb = 0;
        for (int qb = 0; qb < NB_; ++qb) {
            int cnt = 0;
            for (int j = 0; j < NB_; ++j)
                if ((M.m[lyr][qb] >> j) & 1u)
                    T.jlist[lyr][qb][cnt++] = (unsigned char)j;
            int nch = (cnt + CH_ - 1) / CH_;
            if (nch == 1) {
                T.itm_qb[lyr][items] = (unsigned char)qb;
                T.itm_j0[lyr][items] = 0;
                T.itm_jn[lyr][items] = (unsigned char)cnt;
                T.itm_slot[lyr][items] = 0xFF;
                items++;
            } else {
                T.cmb_qb[lyr][ncmb] = (unsigned char)qb;
                T.cmb_slot0[lyr][ncmb] = (unsigned char)slots;
                T.cmb_nch[lyr][ncmb] = (unsigned char)nch;
                ncmb++;
                int base = cnt / nch, rem = cnt % nch, off = 0;
                for (int c = 0; c < nch; ++c) {
                    int cl = base + (c < rem ? 1 : 0);
                    T.itm_qb[lyr][items] = (unsigned char)qb;
                    T.itm_j0[lyr][items] = (unsigned char)off;
                    T.itm_jn[lyr][items] = (unsigned char)cl;
                    T.itm_slot[lyr][items] = (unsigned char)slots;
                    items++; slots++; off += cl;
                }
            }
        }
        T.n_items[lyr] = items;
        T.n_cmb[lyr] = ncmb;
    }
    return T;
}

static constexpr WorkTable WT_HOST = compute_work();
__constant__ WorkTable g_wt = compute_work();

// ---------------------------------------------------------------------------
// Embedding + sinusoidal PE -> bf16 residual stream x
// ---------------------------------------------------------------------------
__global__ __launch_bounds__(256) void embed_kernel(const int* __restrict__ tokens,
                                                    const float* __restrict__ embed,
                                                    short* __restrict__ x) {
    int idx = blockIdx.x * 256 + threadIdx.x;      // < L_*E_/8 = 131072
    int l = idx >> 6;
    int e0 = (idx & 63) * 8;
    float pe[8];
    #pragma unroll
    for (int j = 0; j < 8; ++j) {
        int e = e0 + j;
        int jj = e & 255;
        float div = expf((float)jj * -0.03597789207717895f);  // -ln(10000)/256
        float arg = (float)l * div;
        pe[j] = (e < 256) ? sinf(arg) : cosf(arg);
    }
    #pragma unroll
    for (int b = 0; b < B_; ++b) {
        int tok = tokens[b * L_ + l];
        const float* em = embed + (size_t)tok * E_ + e0;
        f32x4 v0 = *(const f32x4*)em;
        f32x4 v1 = *(const f32x4*)(em + 4);
        bf16x8 pk;
        #pragma unroll
        for (int j = 0; j < 4; ++j) {
            pk[j] = f2bf(v0[j] + pe[j]);
            pk[4 + j] = f2bf(v1[j] + pe[4 + j]);
        }
        *(bf16x8*)(x + ((size_t)(b * L_ + l)) * E_ + e0) = pk;
    }
}

// ---------------------------------------------------------------------------
// LayerNorm: bf16 input, bf16 (OUTBF=1) or fp32 (OUTBF=0) output.
// Wave-per-row (4 rows per 256-thread block, no barriers).
// ---------------------------------------------------------------------------
template<int OUTBF>
__global__ __launch_bounds__(256) void ln_kernel(const short* __restrict__ x,
                                                 const float* __restrict__ gamma,
                                                 const float* __restrict__ beta,
                                                 void* __restrict__ yout) {
    int t = threadIdx.x;
    int lane = t & 63;
    int row = blockIdx.x * 4 + (t >> 6);
    bf16x8 av = *(const bf16x8*)(x + (size_t)row * E_ + lane * 8);
    float a[8];
    #pragma unroll
    for (int j = 0; j < 8; ++j) a[j] = bf2f(av[j]);
    float s = ((a[0] + a[1]) + (a[2] + a[3])) + ((a[4] + a[5]) + (a[6] + a[7]));
    #pragma unroll
    for (int off = 1; off < 64; off <<= 1) s += __shfl_xor(s, off, 64);
    float mu = s * (1.0f / E_);
    float q = 0.0f;
    #pragma unroll
    for (int j = 0; j < 8; ++j) { float d = a[j] - mu; q += d * d; }
    #pragma unroll
    for (int off = 1; off < 64; off <<= 1) q += __shfl_xor(q, off, 64);
    float rstd = rsqrtf(q * (1.0f / E_) + 1e-6f);
    f32x4 g0 = *(const f32x4*)(gamma + lane * 8);
    f32x4 g1 = *(const f32x4*)(gamma + lane * 8 + 4);
    f32x4 b0 = *(const f32x4*)(beta + lane * 8);
    f32x4 b1 = *(const f32x4*)(beta + lane * 8 + 4);
    float o[8];
    #pragma unroll
    for (int j = 0; j < 4; ++j) o[j] = (a[j] - mu) * rstd * g0[j] + b0[j];
    #pragma unroll
    for (int j = 0; j < 4; ++j) o[4 + j] = (a[4 + j] - mu) * rstd * g1[j] + b1[j];
    if (OUTBF) {
        bf16x8 pk;
        #pragma unroll
        for (int j = 0; j < 8; ++j) pk[j] = f2bf(o[j]);
        *(bf16x8*)((short*)yout + (size_t)row * E_ + lane * 8) = pk;
    } else {
        float* yr = (float*)yout + (size_t)row * E_ + lane * 8;
        *(f32x4*)yr = f32x4{o[0], o[1], o[2], o[3]};
        *(f32x4*)(yr + 4) = f32x4{o[4], o[5], o[6], o[7]};
    }
}

// ---------------------------------------------------------------------------
// Weight convert + transpose: Wt[n][k] = bf16(W[k][n] * scale), per layer (z)
// ---------------------------------------------------------------------------
__global__ __launch_bounds__(256) void convT_kernel(const float* __restrict__ W,
                                                    short* __restrict__ Wt,
                                                    int K, int N,
                                                    size_t wStride, size_t wtStride,
                                                    float scale) {
    __shared__ float Ts[64][65];
    const float* Wl = W + blockIdx.z * wStride;
    short* Wtl = Wt + blockIdx.z * wtStride;
    int n0 = blockIdx.x * 64, k0 = blockIdx.y * 64;
    int t = threadIdx.x;
    int c = t & 63, r0 = t >> 6;
    #pragma unroll
    for (int i = 0; i < 16; ++i) {
        int r = r0 * 16 + i;
        Ts[r][c] = Wl[(size_t)(k0 + r) * N + n0 + c] * scale;
    }
    __syncthreads();
    #pragma unroll
    for (int i = 0; i < 16; ++i) {
        int r = r0 * 16 + i;
        Wtl[(size_t)(n0 + r) * K + k0 + c] = f2bf(Ts[c][r]);
    }
}

// ---------------------------------------------------------------------------
// MFMA bf16 GEMM, 2-phase double-buffered (r12-proven schedule, UNCHANGED).
// ---------------------------------------------------------------------------
__device__ __forceinline__ float gelu_tanh(float x) {
    float u = x * (1.5957691216057308f + 0.07135480122394604f * x * x);
    return x / (1.0f + __expf(-u));
}

template<int BM, int BN, int ACT, int OUTBF>
__global__ __launch_bounds__(512) void mgemm_kernel(const short* __restrict__ A,
                                                    const short* __restrict__ Bt,
                                                    const float* __restrict__ bias,
                                                    const short* __restrict__ res,
                                                    short* __restrict__ Cout,
                                                    int M, int N, int K) {
    constexpr int WR = 2, WC = 4;      // 8 waves
    constexpr int FM = BM / WR / 16;
    constexpr int FN = BN / WC / 16;
    constexpr int ASZ = BM * 64;
    constexpr int BSZ = BN * 64;
    constexpr int PAD = 8;
    constexpr int CW = BN + PAD;
    static_assert((size_t)(OUTBF ? BM * CW * 2 : BM * CW * 4) <= (size_t)2 * (ASZ + BSZ) * 2,
                  "epilogue stage must fit in dbuf LDS");
    __shared__ __align__(16) short smem[2 * (ASZ + BSZ)];

    int t = threadIdx.x;
    int w = t >> 6, l = t & 63;
    int l15 = l & 15, lg = l >> 4;
    int wr = w >> 2, wc = w & 3;
    int rowbase = wr * (BM / WR), colbase = wc * (BN / WC);

    int nwg = (int)(gridDim.x * gridDim.y);
    int orig = (int)(blockIdx.y * gridDim.x + blockIdx.x);
    int sid = (orig & 7) * (nwg >> 3) + (orig >> 3);
    int bx = sid % (int)gridDim.x, by = sid / (int)gridDim.x;
    int brow = by * BM, bcol = bx * BN;

    int swz = ((t & 7) ^ ((t >> 3) & 7)) * 8;
    f32x4 acc[FM][FN] = {};

    const int nt = K >> 6;

    auto stage = [&](int buf, int k0) {
        short* Ad = smem + buf * ASZ;
        short* Bd = smem + 2 * ASZ + buf * BSZ;
        #pragma unroll
        for (int it = 0; it < BM / 64; ++it) {
            int row = it * 64 + (t >> 3);
            const short* ga = A + (size_t)(brow + row) * K + k0 + swz;
            __builtin_amdgcn_global_load_lds(
                (const __attribute__((address_space(1))) unsigned int*)ga,
                (__attribute__((address_space(3))) unsigned int*)(Ad + (it * 64 + w * 8) * 64),
                16, 0, 0);
        }
        #pragma unroll
        for (int it = 0; it < BN / 64; ++it) {
            int row = it * 64 + (t >> 3);
            const short* gb = Bt + (size_t)(bcol + row) * K + k0 + swz;
            __builtin_amdgcn_global_load_lds(
                (const __attribute__((address_space(1))) unsigned int*)gb,
                (__attribute__((address_space(3))) unsigned int*)(Bd + (it * 64 + w * 8) * 64),
                16, 0, 0);
        }
    };

    stage(0, 0);
    asm volatile("s_waitcnt vmcnt(0)" ::: "memory");
    __builtin_amdgcn_s_barrier();

    int cur = 0;
    for (int kt = 0; kt < nt; ++kt) {
        if (kt + 1 < nt) stage(cur ^ 1, (kt + 1) << 6);
        const short* Ar = smem + cur * ASZ;
        const short* Br = smem + 2 * ASZ + cur * BSZ;
        #pragma unroll
        for (int kk = 0; kk < 64; kk += 32) {
            bf16x8 af[FM], bfr[FN];
            #pragma unroll
            for (int m = 0; m < FM; ++m)
                af[m] = *(const bf16x8*)(Ar + (rowbase + m * 16 + l15) * 64
                                            + (((kk >> 3) + lg) ^ (l15 & 7)) * 8);
            #pragma unroll
            for (int n = 0; n < FN; ++n)
                bfr[n] = *(const bf16x8*)(Br + (colbase + n * 16 + l15) * 64
                                             + (((kk >> 3) + lg) ^ (l15 & 7)) * 8);
            #pragma unroll
            for (int m = 0; m < FM; ++m)
                #pragma unroll
                for (int n = 0; n < FN; ++n)
                    acc[m][n] = __builtin_amdgcn_mfma_f32_16x16x32_bf16(af[m], bfr[n], acc[m][n], 0, 0, 0);
        }
        asm volatile("s_waitcnt vmcnt(0) lgkmcnt(0)" ::: "memory");
        __builtin_amdgcn_s_barrier();
        cur ^= 1;
    }

    if (OUTBF) {
        short* Cs = smem;
        #pragma unroll
        for (int m = 0; m < FM; ++m) {
            int row = rowbase + m * 16 + lg * 4;
            #pragma unroll
            for (int n = 0; n < FN; ++n) {
                int col = colbase + n * 16 + l15;
                float bv = bias ? bias[bcol + col] : 0.0f;
                #pragma unroll
                for (int r = 0; r < 4; ++r) {
                    float vv = acc[m][n][r] + bv;
                    if (ACT == 1) vv = gelu_tanh(vv);
                    Cs[(row + r) * CW + col] = f2bf(vv);
                }
            }
        }
        __syncthreads();
        #pragma unroll
        for (int it = 0; it < BM * BN / 8 / 512; ++it) {
            int c = it * 512 + t;
            int row = c / (BN / 8), c8 = c % (BN / 8);
            *(bf16x8*)(Cout + (size_t)(brow + row) * N + bcol + c8 * 8) =
                *(const bf16x8*)(Cs + row * CW + c8 * 8);
        }
    } else {
        float* Cs = (float*)smem;              // f32 staging: single rounding
        #pragma unroll
        for (int m = 0; m < FM; ++m) {
            int row = rowbase + m * 16 + lg * 4;
            #pragma unroll
            for (int n = 0; n < FN; ++n) {
                int col = colbase + n * 16 + l15;
                float bv = bias ? bias[bcol + col] : 0.0f;
                #pragma unroll
                for (int r = 0; r < 4; ++r)
                    Cs[(row + r) * CW + col] = acc[m][n][r] + bv;
            }
        }
        __syncthreads();
        #pragma unroll
        for (int it = 0; it < BM * BN / 8 / 512; ++it) {
            int c = it * 512 + t;
            int row = c / (BN / 8), c8 = c % (BN / 8);
            const float* cr = Cs + row * CW + c8 * 8;
            size_t gi = (size_t)(brow + row) * N + bcol + c8 * 8;
            bf16x8 rv = {};
            if (res) rv = *(const bf16x8*)(res + gi);
            bf16x8 outv;
            #pragma unroll
            for (int j = 0; j < 8; ++j) {
                float v = cr[j] + (res ? bf2f(rv[j]) : 0.0f);
                outv[j] = f2bf(v);
            }
            *(bf16x8*)(Cout + gi) = outv;
        }
    }
}

// ---------------------------------------------------------------------------
// Sparse block attention, MFMA bf16, KVBLK=64, swapped QK^T, dbuf K/V LDS.
// Flat 1-D grid + bijective XCD chunk swizzle; tree reductions + defer-max.
// r15-proven version (Pw LDS tile; the r16 shuffle re-layout regressed and
// was reverted).
// ---------------------------------------------------------------------------
#define KSTR 72

__global__ __launch_bounds__(256) void attn_kernel(const short* __restrict__ qkv,
                                                   const int* __restrict__ tokens,
                                                   short* __restrict__ o,
                                                   float* __restrict__ pacc,
                                                   float* __restrict__ pm,
                                                   float* __restrict__ pl,
                                                   int lyr) {
    __shared__ __align__(16) short Ks[2][64][KSTR];
    __shared__ __align__(16) short Vt[2][64][KSTR];
    __shared__ __align__(16) short Pw[4][16][KSTR];
    __shared__ unsigned long long qbits_s;
    __shared__ unsigned long long kbits_s[2];

    int nit = g_wt.n_items[lyr];
    int nwg = (int)gridDim.x;                    // nit * 32, divisible by 8
    int orig = (int)blockIdx.x;
    int sid = (orig & 7) * (nwg >> 3) + (orig >> 3);
    int item = sid % nit;
    int bh = sid / nit;
    int h = bh & 7, b = bh >> 3;

    int qb   = g_wt.itm_qb[lyr][item];
    int j0   = g_wt.itm_j0[lyr][item];
    int jn   = g_wt.itm_jn[lyr][item];
    int slot = g_wt.itm_slot[lyr][item];
    const unsigned char* jl = g_wt.jlist[lyr][qb];

    int t = threadIdx.x;
    int l = t & 63, w = t >> 6;
    int l15 = l & 15, lg = l >> 4;
    int srow = t >> 3, sdb = t & 7;

    if (t < 64) {
        unsigned long long qm = __ballot(tokens[b * L_ + qb * 64 + t] > 0);
        if (t == 0) qbits_s = qm;
    }

    int qrow = qb * 64 + w * 16 + l15;
    const short* qp = qkv + (size_t)(b * L_ + qrow) * 1536 + h * 64;
    bf16x8 qf0 = *(const bf16x8*)(qp + lg * 8);
    bf16x8 qf1 = *(const bf16x8*)(qp + lg * 8 + 32);

    f32x4 acc[4] = {};
    float m_r = -INFINITY, l_r = 0.0f;

    bf16x8 kr0, kr1, vr0, vr1;
    int pn = 0;
    auto LOAD = [&](int ci) {
        int jb = jl[j0 + ci];
        const short* base = qkv + (size_t)(b * L_ + jb * 64 + srow) * 1536 + h * 64;
        kr0 = *(const bf16x8*)(base + 512 + sdb * 8);
        kr1 = *(const bf16x8*)(base + (size_t)32 * 1536 + 512 + sdb * 8);
        vr0 = *(const bf16x8*)(base + 1024 + sdb * 8);
        vr1 = *(const bf16x8*)(base + (size_t)32 * 1536 + 1024 + sdb * 8);
        if (t < 64) pn = tokens[b * L_ + jb * 64 + t];
    };
    auto STORE = [&](int buf) {
        *(bf16x8*)&Ks[buf][srow][sdb * 8] = kr0;
        *(bf16x8*)&Ks[buf][srow + 32][sdb * 8] = kr1;
        #pragma unroll
        for (int j = 0; j < 8; ++j) {
            Vt[buf][sdb * 8 + j][(srow & 7) + 8 * ((srow >> 3) ^ sdb)] = vr0[j];
            Vt[buf][sdb * 8 + j][(srow & 7) + 8 * (((srow >> 3) + 4) ^ sdb)] = vr1[j];
        }
        if (t < 64) {
            unsigned long long km = __ballot(pn > 0);
            if (t == 0) kbits_s[buf] = km;
        }
    };

    LOAD(0);
    STORE(0);
    if (jn > 1) LOAD(1);
    __syncthreads();

    int cur = 0;
    for (int ci = 0; ci < jn; ++ci) {
        f32x4 sacc[4];
        __builtin_amdgcn_s_setprio(1);
        #pragma unroll
        for (int f = 0; f < 4; ++f) {
            bf16x8 kk0 = *(const bf16x8*)&Ks[cur][16 * f + l15][lg * 8];
            bf16x8 kk1 = *(const bf16x8*)&Ks[cur][16 * f + l15][lg * 8 + 32];
            f32x4 z = {};
            z = __builtin_amdgcn_mfma_f32_16x16x32_bf16(kk0, qf0, z, 0, 0, 0);
            z = __builtin_amdgcn_mfma_f32_16x16x32_bf16(kk1, qf1, z, 0, 0, 0);
            sacc[f] = z;
        }
        __builtin_amdgcn_s_setprio(0);

        unsigned long long kb = kbits_s[cur];
        bool pq = (qbits_s >> (w * 16 + l15)) & 1ull;
        unsigned vm = 0;
        #pragma unroll
        for (int f = 0; f < 4; ++f)
            vm |= ((unsigned)(kb >> (16 * f + 4 * lg)) & 0xFu) << (4 * f);
        if (!pq) vm = 0;

        float sv[16];
        #pragma unroll
        for (int i = 0; i < 16; ++i)
            sv[i] = ((vm >> i) & 1u) ? sacc[i >> 2][i & 3] : -INFINITY;
        float t8[8], t4[4];
        #pragma unroll
        for (int i = 0; i < 8; ++i) t8[i] = fmaxf(sv[i], sv[i + 8]);
        #pragma unroll
        for (int i = 0; i < 4; ++i) t4[i] = fmaxf(t8[i], t8[i + 4]);
        float mx = fmaxf(fmaxf(t4[0], t4[1]), fmaxf(t4[2], t4[3]));
        mx = fmaxf(mx, __shfl_xor(mx, 16, 64));
        mx = fmaxf(mx, __shfl_xor(mx, 32, 64));

        bool defer = __all((mx <= m_r + 8.0f) && (m_r > -1e30f));
        float nm = defer ? m_r : fmaxf(m_r, mx);

        float pv[16];
        #pragma unroll
        for (int i = 0; i < 16; ++i)
            pv[i] = ((vm >> i) & 1u) ? __expf(sv[i] - nm) : 0.0f;
        float s8[8], s4[4];
        #pragma unroll
        for (int i = 0; i < 8; ++i) s8[i] = pv[i] + pv[i + 8];
        #pragma unroll
        for (int i = 0; i < 4; ++i) s4[i] = s8[i] + s8[i + 4];
        float sum = (s4[0] + s4[1]) + (s4[2] + s4[3]);
        sum += __shfl_xor(sum, 16, 64);
        sum += __shfl_xor(sum, 32, 64);

        if (defer) {
            l_r += sum;
        } else {
            float al = (nm == -INFINITY) ? 1.0f : __expf(m_r - nm);
            m_r = nm;
            l_r = l_r * al + sum;
            float alr[4];
            #pragma unroll
            for (int r = 0; r < 4; ++r) alr[r] = __shfl(al, lg * 4 + r, 64);
            #pragma unroll
            for (int fd = 0; fd < 4; ++fd)
                #pragma unroll
                for (int r = 0; r < 4; ++r) acc[fd][r] *= alr[r];
        }

        #pragma unroll
        for (int f = 0; f < 4; ++f) {
            bf16x4 pk;
            #pragma unroll
            for (int r = 0; r < 4; ++r) pk[r] = f2bf(pv[4 * f + r]);
            *(bf16x4*)&Pw[w][l15][16 * f + 4 * lg] = pk;
        }

        bf16x8 pa0 = *(const bf16x8*)&Pw[w][l15][lg * 8];
        bf16x8 pa1 = *(const bf16x8*)&Pw[w][l15][lg * 8 + 32];
        __builtin_amdgcn_s_setprio(1);
        #pragma unroll
        for (int fd = 0; fd < 4; ++fd) {
            int dd = 16 * fd + l15;
            bf16x8 vv0 = *(const bf16x8*)&Vt[cur][dd][8 * (lg ^ (dd >> 3))];
            bf16x8 vv1 = *(const bf16x8*)&Vt[cur][dd][8 * ((4 + lg) ^ (dd >> 3))];
            acc[fd] = __builtin_amdgcn_mfma_f32_16x16x32_bf16(pa0, vv0, acc[fd], 0, 0, 0);
            acc[fd] = __builtin_amdgcn_mfma_f32_16x16x32_bf16(pa1, vv1, acc[fd], 0, 0, 0);
        }
        __builtin_amdgcn_s_setprio(0);

        if (ci + 1 < jn) {
            STORE(cur ^ 1);
            if (ci + 2 < jn) LOAD(ci + 2);
        }
        __syncthreads();
        cur ^= 1;
    }

    float lrr[4], mrr[4];
    #pragma unroll
    for (int r = 0; r < 4; ++r) {
        lrr[r] = __shfl(l_r, lg * 4 + r, 64);
        mrr[r] = __shfl(m_r, lg * 4 + r, 64);
    }
    unsigned long long qbits = qbits_s;

    if (slot == 0xFF) {
        #pragma unroll
        for (int r = 0; r < 4; ++r) {
            int rw = lg * 4 + r;
            int gl = qb * 64 + w * 16 + rw;
            size_t ob = (size_t)(b * L_ + gl) * 512 + h * 64 + l15;
            bool ok = ((qbits >> (w * 16 + rw)) & 1ull) && (lrr[r] > 0.0f);
            if (ok) {
                float inv = 1.0f / lrr[r];
                #pragma unroll
                for (int fd = 0; fd < 4; ++fd) o[ob + 16 * fd] = f2bf(acc[fd][r] * inv);
            } else {
                #pragma unroll
                for (int fd = 0; fd < 4; ++fd) {
                    float s = 0.0f;
                    for (int m = 0; m < L_; ++m)
                        s += bf2f(qkv[(size_t)(b * L_ + m) * 1536 + 1024 + h * 64 + 16 * fd + l15]);
                    o[ob + 16 * fd] = f2bf(s * (1.0f / L_));
                }
            }
        }
    } else {
        size_t pb = ((size_t)slot * B_ + b) * H_ + h;
        #pragma unroll
        for (int r = 0; r < 4; ++r) {
            int rloc = w * 16 + lg * 4 + r;
            #pragma unroll
            for (int fd = 0; fd < 4; ++fd)
                pacc[pb * 4096 + (size_t)rloc * 64 + 16 * fd + l15] = acc[fd][r];
            if (l15 == 0) {
                pm[pb * 64 + rloc] = mrr[r];
                pl[pb * 64 + rloc] = lrr[r];
            }
        }
    }
}

// ---------------------------------------------------------------------------
// Combine partial flash results for split q-blocks.
// ---------------------------------------------------------------------------
__global__ __launch_bounds__(256) void attn_combine(const short* __restrict__ qkv,
                                                    const int* __restrict__ tokens,
                                                    short* __restrict__ o,
                                                    const float* __restrict__ pacc,
                                                    const float* __restrict__ pm,
                                                    const float* __restrict__ pl,
                                                    int lyr) {
    int ci = blockIdx.x, h = blockIdx.y, b = blockIdx.z;
    int qb  = g_wt.cmb_qb[lyr][ci];
    int s0  = g_wt.cmb_slot0[lyr][ci];
    int nch = g_wt.cmb_nch[lyr][ci];
    int t = threadIdx.x;
    int r = t >> 2, dq = t & 3;
    int grow = qb * 64 + r;
    bool pq = tokens[b * L_ + grow] > 0;
    float M = -INFINITY;
    for (int c = 0; c < nch; ++c)
        M = fmaxf(M, pm[(((size_t)(s0 + c) * B_ + b) * H_ + h) * 64 + r]);
    size_t ob = (size_t)(b * L_ + grow) * 512 + h * 64 + dq * 16;
    if (pq && M > -1e30f) {
        float lsum = 0.0f;
        float accd[16] = {};
        for (int c = 0; c < nch; ++c) {
            size_t pb = ((size_t)(s0 + c) * B_ + b) * H_ + h;
            float wgt = __expf(pm[pb * 64 + r] - M);
            lsum += pl[pb * 64 + r] * wgt;
            const float* pa = pacc + pb * 4096 + (size_t)r * 64 + dq * 16;
            #pragma unroll
            for (int j = 0; j < 16; ++j) accd[j] += pa[j] * wgt;
        }
        float inv = 1.0f / lsum;
        #pragma unroll
        for (int j = 0; j < 16; ++j) o[ob + j] = f2bf(accd[j] * inv);
    } else {
        #pragma unroll
        for (int j = 0; j < 16; ++j) {
            float s = 0.0f;
            for (int m = 0; m < L_; ++m)
                s += bf2f(qkv[(size_t)(b * L_ + m) * 1536 + 1024 + h * 64 + dq * 16 + j]);
            o[ob + j] = f2bf(s * (1.0f / L_));
        }
    }
}

// ---------------------------------------------------------------------------
// Launch
// ---------------------------------------------------------------------------
extern "C" void kernel_launch(void* const* d_in, const int* in_sizes, int n_in,
                              void* d_out, int out_size, void* d_ws, size_t ws_size,
                              hipStream_t stream) {
    (void)in_sizes; (void)n_in; (void)out_size; (void)ws_size;
    const int*   tokens = (const int*)d_in[0];
    const float* embed  = (const float*)d_in[1];
    const float* ln1_s  = (const float*)d_in[2];
    const float* ln1_b  = (const float*)d_in[3];
    const float* wq     = (const float*)d_in[4];
    const float* wk     = (const float*)d_in[5];
    const float* wv     = (const float*)d_in[6];
    const float* wo     = (const float*)d_in[7];
    const float* ln2_s  = (const float*)d_in[8];
    const float* ln2_b  = (const float*)d_in[9];
    const float* w1     = (const float*)d_in[10];
    const float* b1     = (const float*)d_in[11];
    const float* w2     = (const float*)d_in[12];
    const float* b2     = (const float*)d_in[13];
    const float* lnf_s  = (const float*)d_in[14];
    const float* lnf_b  = (const float*)d_in[15];
    float* out = (float*)d_out;

    const size_t BLE = (size_t)B_ * L_ * E_;              // 4,194,304
    char* ws = (char*)d_ws;
    short* x    = (short*)ws;                             // bf16 residual, 8 MB
    short* yb   = x + BLE;                                //  8 MB
    short* R    = yb + BLE;                               // 32 MB (qkv+ob / hb)
    short* qkv  = R;
    short* ob   = R + 3 * BLE;
    short* hb   = R;
    short* qkvt = R + 4 * BLE;                            // bf16 weights
    short* wot  = qkvt + (size_t)NL_ * 1536 * 512;
    short* w1t  = wot + (size_t)NL_ * 512 * 512;
    short* w2t  = w1t + (size_t)NL_ * 2048 * 512;
    float* pacc = (float*)(w2t + (size_t)NL_ * 512 * 2048);   // 8 slots x B x H x 4096 f32
    float* pm   = pacc + (size_t)8 * B_ * H_ * 4096;
    float* pl   = pm + (size_t)8 * B_ * H_ * 64;

    convT_kernel<<<dim3(8, 8, NL_), 256, 0, stream>>>(wq, qkvt,          512, 512, 262144, 786432, 0.125f);
    convT_kernel<<<dim3(8, 8, NL_), 256, 0, stream>>>(wk, qkvt + 262144, 512, 512, 262144, 786432, 1.0f);
    convT_kernel<<<dim3(8, 8, NL_), 256, 0, stream>>>(wv, qkvt + 524288, 512, 512, 262144, 786432, 1.0f);
    convT_kernel<<<dim3(8, 8, NL_), 256, 0, stream>>>(wo, wot,           512, 512, 262144, 262144, 1.0f);
    convT_kernel<<<dim3(32, 8, NL_), 256, 0, stream>>>(w1, w1t,          512, 2048, 1048576, 1048576, 1.0f);
    convT_kernel<<<dim3(8, 32, NL_), 256, 0, stream>>>(w2, w2t,          2048, 512, 1048576, 1048576, 1.0f);

    embed_kernel<<<(L_ * E_ / 8) / 256, 256, 0, stream>>>(tokens, embed, x);

    const int MR = B_ * L_;
    const int LNG = MR / 4;                                // 2048 blocks
    for (int lyr = 0; lyr < NL_; ++lyr) {
        ln_kernel<1><<<LNG, 256, 0, stream>>>(x, ln1_s + lyr * E_, ln1_b + lyr * E_, yb);
        mgemm_kernel<128, 128, 0, 1><<<dim3(12, 64), 512, 0, stream>>>(
            yb, qkvt + (size_t)lyr * 786432, nullptr, nullptr, qkv, MR, 1536, 512);
        attn_kernel<<<dim3(WT_HOST.n_items[lyr] * H_ * B_), 256, 0, stream>>>(
            qkv, tokens, ob, pacc, pm, pl, lyr);
        attn_combine<<<dim3(WT_HOST.n_cmb[lyr], H_, B_), 256, 0, stream>>>(
            qkv, tokens, ob, pacc, pm, pl, lyr);
        mgemm_kernel<64, 128, 0, 0><<<dim3(4, 128), 512, 0, stream>>>(
            ob, wot + (size_t)lyr * 262144, nullptr, x, x, MR, 512, 512);
        ln_kernel<1><<<LNG, 256, 0, stream>>>(x, ln2_s + lyr * E_, ln2_b + lyr * E_, yb);
        mgemm_kernel<128, 128, 1, 1><<<dim3(16, 64), 512, 0, stream>>>(
            yb, w1t + (size_t)lyr * 1048576, b1 + (size_t)lyr * M_, nullptr, hb, MR, 2048, 512);
        mgemm_kernel<64, 128, 0, 0><<<dim3(4, 128), 512, 0, stream>>>(
            hb, w2t + (size_t)lyr * 1048576, b2 + (size_t)lyr * E_, x, x, MR, 512, 2048);
    }
    ln_kernel<0><<<LNG, 256, 0, stream>>>(x, lnf_s, lnf_b, out);
}